// Round 12
// baseline (528.393 us; speedup 1.0000x reference)
//
#include <hip/hip_runtime.h>

#define N_NODES 5000
#define NH 8
#define MAXDEG 128

typedef unsigned short u16;
typedef short bf16x8 __attribute__((ext_vector_type(8)));
typedef float f32x4 __attribute__((ext_vector_type(4)));

static __device__ __forceinline__ float selu_f(float x) {
    const float sc = 1.0507009873554805f;
    const float al = 1.6732632423543772f;
    return x > 0.f ? sc * x : sc * al * (__expf(x) - 1.f);
}

static __device__ __forceinline__ u16 f2bf(float x) {
    union { float f; unsigned u; } v; v.f = x;
    unsigned r = v.u + 0x7fff + ((v.u >> 16) & 1);
    return (u16)(r >> 16);
}

static __device__ __forceinline__ float bf2f(unsigned hi16) {
    union { unsigned u; float f; } v; v.u = hi16 << 16;
    return v.f;
}

// async global->LDS, 16B per lane; LDS dest is wave-uniform base + lane*16
#define GL2LDS16(gp, lp)                                                        \
    __builtin_amdgcn_global_load_lds(                                           \
        (const __attribute__((address_space(1))) void*)(gp),                    \
        (__attribute__((address_space(3))) void*)(lp), 16, 0, 0)

// intra-wave LDS fence (lockstep wave64 handoff, no s_barrier needed)
#define WAVE_LDS_FENCE() asm volatile("s_waitcnt lgkmcnt(0)" ::: "memory")

// ---------------- k_prep: vectorized fold + fat wtr + (tail) zero counters ----
__global__ __launch_bounds__(256) void k_prep(
        const float* W1, const float* W2, const float* W3, const float* W4,
        const float* s1, const float* s2, const float* s3, const float* s4,
        const float* d1, const float* d2, const float* d3, const float* d4,
        float* __restrict__ fsAll, float* __restrict__ fdAll,
        u16* T1, u16* T2, u16* T3, int* __restrict__ cnt) {
    const int Ks[4] = {258, 516, 262, 136};
    const int Cs[4] = {512, 256, 128, 20};
    const int NB0 = 16 * 18;
    const int NB1 = 8  * 34;
    const int NB2 = 4  * 18;
    const int NWTR = NB0 + NB1 + NB2;   // 632
    int bid = blockIdx.x;
    if (bid < 516) {
        int li = bid / 129;
        int k = (bid % 129) * 4 + (threadIdx.x >> 6);
        int lane = threadIdx.x & 63;
        if (k >= Ks[li]) return;
        const float* W  = (li == 0) ? W1 : (li == 1) ? W2 : (li == 2) ? W3 : W4;
        const float* as = (li == 0) ? s1 : (li == 1) ? s2 : (li == 2) ? s3 : s4;
        const float* ad = (li == 0) ? d1 : (li == 1) ? d2 : (li == 2) ? d3 : d4;
        int C = Cs[li];
        float s[8] = {0.f,0.f,0.f,0.f,0.f,0.f,0.f,0.f};
        float d[8] = {0.f,0.f,0.f,0.f,0.f,0.f,0.f,0.f};
        const float* wr = W + (size_t)k * 8 * C;
        for (int c = lane * 4; c < C; c += 256) {
            #pragma unroll
            for (int h = 0; h < 8; ++h) {
                float4 wv = *(const float4*)(wr + h * C + c);
                float4 sv = *(const float4*)(as + h * C + c);
                float4 dv = *(const float4*)(ad + h * C + c);
                s[h] += wv.x * sv.x + wv.y * sv.y + wv.z * sv.z + wv.w * sv.w;
                d[h] += wv.x * dv.x + wv.y * dv.y + wv.z * dv.z + wv.w * dv.w;
            }
        }
        #pragma unroll
        for (int off = 32; off >= 1; off >>= 1) {
            #pragma unroll
            for (int h = 0; h < 8; ++h) {
                s[h] += __shfl_xor(s[h], off);
                d[h] += __shfl_xor(d[h], off);
            }
        }
        if (lane == 0) {
            float* fo = fsAll + (size_t)li * 516 * 8 + k * 8;
            float* go = fdAll + (size_t)li * 516 * 8 + k * 8;
            #pragma unroll
            for (int h = 0; h < 8; ++h) { fo[h] = s[h]; go[h] = d[h]; }
        }
    } else if (bid < 516 + NWTR) {
        int w = bid - 516;
        int li, rem, nc;
        if (w < NB0)            { li = 0; rem = w;             nc = 16; }
        else if (w < NB0 + NB1) { li = 1; rem = w - NB0;       nc = 8;  }
        else                    { li = 2; rem = w - NB0 - NB1; nc = 4;  }
        const int Kps[3] = {288, 544, 288};
        int C = Cs[li], K = Ks[li], Kp = Kps[li], KK = 8 * Kp;
        int c0 = (rem % nc) * 32;
        int jb = (rem / nc) * 128;
        const float* W = (li == 0) ? W1 : (li == 1) ? W2 : W3;
        u16* Wt2 = (li == 0) ? T1 : (li == 1) ? T2 : T3;
        __shared__ float tile[32][33];
        int t = threadIdx.x;
        int kr = t >> 3, f = t & 7;
        #pragma unroll
        for (int jt = 0; jt < 4; ++jt) {
            int j0 = jb + jt * 32;
            int h = j0 / Kp, k0 = j0 % Kp;
            int gk = k0 + kr;
            float4 v = {0.f, 0.f, 0.f, 0.f};
            if (gk < K) v = *(const float4*)(W + (size_t)gk * (8 * C) + h * C + c0 + f * 4);
            tile[kr][f * 4 + 0] = v.x;
            tile[kr][f * 4 + 1] = v.y;
            tile[kr][f * 4 + 2] = v.z;
            tile[kr][f * 4 + 3] = v.w;
            __syncthreads();
            int cr = kr, kc0 = f * 4;
            ushort4 o;
            o.x = f2bf(tile[kc0 + 0][cr]);
            o.y = f2bf(tile[kc0 + 1][cr]);
            o.z = f2bf(tile[kc0 + 2][cr]);
            o.w = f2bf(tile[kc0 + 3][cr]);
            *(ushort4*)(Wt2 + (size_t)(c0 + cr) * KK + j0 + kc0) = o;
            __syncthreads();
        }
    } else {
        for (int i = threadIdx.x; i < N_NODES; i += 256) cnt[i] = 0;
    }
}

// ---------------- k_fmf1b: bucketed fill + layer-1 mf in one dispatch ----------------
// Writes layer-1 es/ed/afb (buffers with parity 1).
__global__ __launch_bounds__(256) void k_fmf1b(
        const int* __restrict__ ei, int* __restrict__ cnt,
        int* __restrict__ ssrcb, int E, int Esz, int gE,
        const float* __restrict__ data, const float* __restrict__ W0,
        const float* __restrict__ b0,
        const float* __restrict__ fs, const float* __restrict__ fd,
        u16* __restrict__ afb, float* __restrict__ es, float* __restrict__ ed,
        float* __restrict__ c0out) {
    int bid = blockIdx.x, t = threadIdx.x;
    if (bid < gE) {
        int e = bid * 256 + t;
        if (e >= Esz) return;
        int src, dst;
        if (e < E) { src = ei[e]; dst = ei[E + e]; }
        else       { src = e - E; dst = src; }
        int pos = atomicAdd(&cnt[dst], 1);
        if (pos < MAXDEG) ssrcb[dst * MAXDEG + pos] = src;
        return;
    }
    const int FC = 256, K = 258, Kp = 288;
    int n = bid - gE;
    __shared__ float drow[10];
    if (t < 10) drow[t] = data[n * 10 + t];
    __syncthreads();
    float pes[8] = {0.f,0.f,0.f,0.f,0.f,0.f,0.f,0.f};
    float ped[8] = {0.f,0.f,0.f,0.f,0.f,0.f,0.f,0.f};
    u16* rowb = afb + (size_t)n * Kp;
    for (int cf2 = t; 2 * cf2 < FC; cf2 += 256) {
        int cf = 2 * cf2;
        float2 bb = *(const float2*)(b0 + cf);
        float v0 = bb.x, v1 = bb.y;
        #pragma unroll
        for (int k = 0; k < 10; ++k) {
            float2 ww = *(const float2*)(W0 + k * 256 + cf);
            v0 += drow[k] * ww.x;
            v1 += drow[k] * ww.y;
        }
        v0 = selu_f(v0); v1 = selu_f(v1);
        int c = 2 + cf;
        *(unsigned*)(rowb + c) = (unsigned)f2bf(v0) | ((unsigned)f2bf(v1) << 16);
        const float* fsr = fs + c * 8;
        const float* fdr = fd + c * 8;
        #pragma unroll
        for (int h = 0; h < 8; ++h) {
            pes[h] += v0 * fsr[h] + v1 * fsr[8 + h];
            ped[h] += v0 * fdr[h] + v1 * fdr[8 + h];
        }
    }
    if (t < 2) {
        float v = drow[t];
        c0out[n * 2 + t] = v;
        rowb[t] = f2bf(v);
        #pragma unroll
        for (int h = 0; h < 8; ++h) { pes[h] += v * fs[t * 8 + h]; ped[h] += v * fd[t * 8 + h]; }
    }
    for (int c = K + t; c < Kp; c += 256) rowb[c] = 0;
    #pragma unroll
    for (int off = 32; off >= 1; off >>= 1) {
        #pragma unroll
        for (int h = 0; h < 8; ++h) {
            pes[h] += __shfl_xor(pes[h], off);
            ped[h] += __shfl_xor(ped[h], off);
        }
    }
    __shared__ float red[4][16];
    int wv = t >> 6, ln = t & 63;
    if (ln == 0) {
        #pragma unroll
        for (int h = 0; h < 8; ++h) { red[wv][h] = pes[h]; red[wv][8 + h] = ped[h]; }
    }
    __syncthreads();
    if (t < 16) {
        float s = red[0][t] + red[1][t] + red[2][t] + red[3][t];
        if (t < 8) es[n * 8 + t] = s;
        else       ed[n * 8 + (t - 8)] = s;
    }
}

// ---------------- gag v3: WAVE per node + next-layer init epilogue --------------
// Same softmax/gather/coords as proven k_gag2; epilogue additionally:
//  - computes clamped cnext in ALL lanes (oc wave-uniform post-butterfly)
//  - INITS next-layer es/ed with the coords contribution (lanes 0..7)
//  - writes next-layer afb coords + zero pad (if afbN != null)
// Runs strictly before gemm (stream order), which atomicAdds the feature part.
template <int S>
__global__ __launch_bounds__(256) void k_gag3(const float* __restrict__ es,
                            const float* __restrict__ ed,
                            const int* __restrict__ cnt, const int* __restrict__ ssrcb,
                            const float* __restrict__ cprev, const u16* __restrict__ afb,
                            u16* __restrict__ g, float* __restrict__ cnext, int Kp,
                            int np1, int K1, int Kp1,
                            const float* __restrict__ fs1, const float* __restrict__ fd1,
                            float* __restrict__ esN, float* __restrict__ edN,
                            u16* __restrict__ afbN,
                            const float* __restrict__ p2, const float* __restrict__ p3) {
    __shared__ float la_s[4][128 * 8];
    __shared__ int   ls_s[4][128];
    __shared__ float linv_s[4][8];
    int w4 = threadIdx.x >> 6, lane = threadIdx.x & 63;
    int n = blockIdx.x * 4 + w4;
    if (n >= N_NODES) return;
    float* la = la_s[w4];
    int*   ls = ls_s[w4];
    float* linv = linv_s[w4];

    int deg = cnt[n];
    if (deg > MAXDEG) deg = MAXDEG;
    const int* row = ssrcb + (size_t)n * MAXDEG;
    for (int i = lane; i < deg; i += 64) ls[i] = row[i];
    WAVE_LDS_FENCE();

    int h = lane & 7, ei = lane >> 3;
    float edh = ed[n * 8 + h];
    float m = -1e30f;
    for (int b = 0; b < deg; b += 8) {
        int e = b + ei;
        if (e < deg) {
            float x = es[ls[e] * 8 + h] + edh;
            x = x > 0.f ? x : 0.2f * x;
            la[e * 8 + h] = x;
            m = fmaxf(m, x);
        }
    }
    m = fmaxf(m, __shfl_xor(m, 8));
    m = fmaxf(m, __shfl_xor(m, 16));
    m = fmaxf(m, __shfl_xor(m, 32));
    WAVE_LDS_FENCE();
    float ssum = 0.f;
    for (int b = 0; b < deg; b += 8) {
        int e = b + ei;
        if (e < deg) {
            float v = __expf(la[e * 8 + h] - m);
            la[e * 8 + h] = v;
            ssum += v;
        }
    }
    ssum += __shfl_xor(ssum, 8);
    ssum += __shfl_xor(ssum, 16);
    ssum += __shfl_xor(ssum, 32);
    if (lane < 8) linv[lane] = 1.f / ssum;
    WAVE_LDS_FENCE();

    int nW = Kp >> 1;
    float linv8[8];
    #pragma unroll
    for (int h2 = 0; h2 < 8; ++h2) linv8[h2] = linv[h2];

    float acc[8][2 * S];
    #pragma unroll
    for (int h2 = 0; h2 < 8; ++h2)
        #pragma unroll
        for (int s = 0; s < 2 * S; ++s) acc[h2][s] = 0.f;
    int e = 0;
    for (; e + 3 < deg; e += 4) {
        const unsigned* r0 = (const unsigned*)(afb + (size_t)ls[e] * Kp);
        const unsigned* r1 = (const unsigned*)(afb + (size_t)ls[e + 1] * Kp);
        const unsigned* r2 = (const unsigned*)(afb + (size_t)ls[e + 2] * Kp);
        const unsigned* r3 = (const unsigned*)(afb + (size_t)ls[e + 3] * Kp);
        unsigned v0[S], v1[S], v2[S], v3[S];
        #pragma unroll
        for (int s = 0; s < S; ++s) {
            int w = lane + 64 * s;
            bool ok = (w < nW);
            v0[s] = ok ? r0[w] : 0u;
            v1[s] = ok ? r1[w] : 0u;
            v2[s] = ok ? r2[w] : 0u;
            v3[s] = ok ? r3[w] : 0u;
        }
        float a0[8], a1[8], a2[8], a3[8];
        #pragma unroll
        for (int h2 = 0; h2 < 8; ++h2) {
            a0[h2] = la[(e + 0) * 8 + h2];
            a1[h2] = la[(e + 1) * 8 + h2];
            a2[h2] = la[(e + 2) * 8 + h2];
            a3[h2] = la[(e + 3) * 8 + h2];
        }
        #pragma unroll
        for (int s = 0; s < S; ++s) {
            float x0 = bf2f(v0[s] & 0xffff), y0 = bf2f(v0[s] >> 16);
            float x1 = bf2f(v1[s] & 0xffff), y1 = bf2f(v1[s] >> 16);
            float x2 = bf2f(v2[s] & 0xffff), y2 = bf2f(v2[s] >> 16);
            float x3 = bf2f(v3[s] & 0xffff), y3 = bf2f(v3[s] >> 16);
            #pragma unroll
            for (int h2 = 0; h2 < 8; ++h2) {
                acc[h2][2 * s]     += a0[h2] * x0 + a1[h2] * x1 + a2[h2] * x2 + a3[h2] * x3;
                acc[h2][2 * s + 1] += a0[h2] * y0 + a1[h2] * y1 + a2[h2] * y2 + a3[h2] * y3;
            }
        }
    }
    for (; e < deg; ++e) {
        const unsigned* r0 = (const unsigned*)(afb + (size_t)ls[e] * Kp);
        unsigned v0[S];
        #pragma unroll
        for (int s = 0; s < S; ++s) {
            int w = lane + 64 * s;
            v0[s] = (w < nW) ? r0[w] : 0u;
        }
        float a0[8];
        #pragma unroll
        for (int h2 = 0; h2 < 8; ++h2) a0[h2] = la[e * 8 + h2];
        #pragma unroll
        for (int s = 0; s < S; ++s) {
            float x0 = bf2f(v0[s] & 0xffff), y0 = bf2f(v0[s] >> 16);
            #pragma unroll
            for (int h2 = 0; h2 < 8; ++h2) {
                acc[h2][2 * s]     += a0[h2] * x0;
                acc[h2][2 * s + 1] += a0[h2] * y0;
            }
        }
    }
    unsigned* grw = (unsigned*)(g + (size_t)n * 8 * Kp);
    #pragma unroll
    for (int s = 0; s < S; ++s) {
        int w = lane + 64 * s;
        if (w < nW) {
            #pragma unroll
            for (int h2 = 0; h2 < 8; ++h2) {
                float iv = linv8[h2];
                unsigned lo = f2bf(acc[h2][2 * s] * iv);
                unsigned hi = f2bf(acc[h2][2 * s + 1] * iv);
                grw[h2 * nW + w] = lo | (hi << 16);
            }
        }
    }
    float oc0 = 0.f, oc1 = 0.f;
    for (int i = lane; i < deg; i += 64) {
        float wsum = 0.f;
        #pragma unroll
        for (int h2 = 0; h2 < 8; ++h2) wsum += la[i * 8 + h2] * linv8[h2];
        int src = ls[i];
        oc0 += wsum * cprev[src * 2];
        oc1 += wsum * cprev[src * 2 + 1];
    }
    #pragma unroll
    for (int off = 1; off <= 32; off <<= 1) {
        oc0 += __shfl_xor(oc0, off);
        oc1 += __shfl_xor(oc1, off);
    }
    // ---- epilogue: cnext + next-layer init (all lanes hold oc0/oc1) ----
    float a0 = cprev[n * 2], a1 = cprev[n * 2 + 1];
    float cn0 = (a0 == 0.f) ? 0.f : ((a0 == 1.f) ? 1.f : oc0 * 0.025f);
    float cn1 = (a1 == 1.f) ? 1.f : ((a1 == 0.f) ? 0.f : oc1 * 0.025f);
    if (lane == 0) { cnext[n * 2] = cn0; cnext[n * 2 + 1] = cn1; }
    float cv[8];
    cv[0] = cn0; cv[1] = cn1;
    cv[2] = a0;  cv[3] = a1;          // coords pair j=1 = cprev
    cv[4] = 0.f; cv[5] = 0.f; cv[6] = 0.f; cv[7] = 0.f;
    if (np1 >= 3) { cv[4] = p2[n * 2]; cv[5] = p2[n * 2 + 1]; }
    if (np1 >= 4) { cv[6] = p3[n * 2]; cv[7] = p3[n * 2 + 1]; }
    if (lane < 8) {
        float se = 0.f, sd = 0.f;
        for (int t2 = 0; t2 < 2 * np1; ++t2) {
            se += cv[t2] * fs1[t2 * 8 + lane];
            sd += cv[t2] * fd1[t2 * 8 + lane];
        }
        esN[n * 8 + lane] = se;
        edN[n * 8 + lane] = sd;
    }
    if (afbN) {
        if (lane < 2 * np1) afbN[(size_t)n * Kp1 + lane] = f2bf(cv[lane]);
        for (int c = K1 + lane; c < Kp1; c += 64) afbN[(size_t)n * Kp1 + c] = 0;
    }
}

// ---------------- k_gemm_f: split=1 GEMM with fused mf epilogue ----------------
// Full-K per block (3-deep pipelined gl2lds, proven loop body unchanged).
// Epilogue: v = selu(acc*0.125 + bias[cf]); writes next-layer afb features (bf16)
// and atomicAdds the feature contribution to next-layer es/ed (initialized by the
// preceding gag dispatch). Garbage rows (>= M) never store (guards); their NaNs
// stay within their own row's lanes (butterfly is over l16 = columns only).
__global__ __launch_bounds__(256) void k_gemm_f(const u16* __restrict__ A,
                                                const u16* __restrict__ Bt,
                                                int M, int KK, int NC, int nbx,
                                                const float* __restrict__ bias,
                                                int np1, int Kp1,
                                                const float* __restrict__ fs1,
                                                const float* __restrict__ fd1,
                                                float* __restrict__ esN,
                                                float* __restrict__ edN,
                                                u16* __restrict__ afbN) {
    __shared__ u16 As[3][128 * 32];
    __shared__ u16 Bs[3][128 * 32];
    int tid = threadIdx.x;
    int wave = tid >> 6, lane = tid & 63;

    int T = gridDim.x;
    int per8 = T >> 3;
    int o = blockIdx.x;
    int oo = (o & 7) * per8 + (o >> 3);
    int by = oo / nbx;
    int bx = oo - by * nbx;

    int bm = by * 128, bn = bx * 128;
    int wm = (wave >> 1) * 64, wn = (wave & 1) * 64;
    int l16 = lane & 15, q = lane >> 4;
    f32x4 acc[4][4] = {};

    int seg0 = wave * 128 + lane;
    int seg1 = seg0 + 64;
    int row0 = seg0 >> 2, sq0 = (seg0 & 3) ^ (row0 & 3);
    int row1 = seg1 >> 2, sq1 = (seg1 & 3) ^ (row1 & 3);
    const u16* ga0 = A  + (size_t)(bm + row0) * KK + sq0 * 8;
    const u16* ga1 = A  + (size_t)(bm + row1) * KK + sq1 * 8;
    const u16* gb0 = Bt + (size_t)(bn + row0) * KK + sq0 * 8;
    const u16* gb1 = Bt + (size_t)(bn + row1) * KK + sq1 * 8;
    int lo0 = (wave * 2 + 0) * 512;
    int lo1 = (wave * 2 + 1) * 512;

#define STAGE_T(buf, kk)                          \
    do {                                          \
        GL2LDS16(ga0 + (kk), &As[buf][lo0]);      \
        GL2LDS16(ga1 + (kk), &As[buf][lo1]);      \
        GL2LDS16(gb0 + (kk), &Bs[buf][lo0]);      \
        GL2LDS16(gb1 + (kk), &Bs[buf][lo1]);      \
    } while (0)

    STAGE_T(0, 0);
    if (32 < KK) STAGE_T(1, 32);
    int cur = 0;
    for (int k0 = 0; k0 < KK; k0 += 32) {
        if (k0 + 64 < KK) {
            int nb = cur + 2; if (nb >= 3) nb -= 3;
            STAGE_T(nb, k0 + 64);
            asm volatile("s_waitcnt vmcnt(8)" ::: "memory");
        } else if (k0 + 32 < KK) {
            asm volatile("s_waitcnt vmcnt(4)" ::: "memory");
        } else {
            asm volatile("s_waitcnt vmcnt(0)" ::: "memory");
        }
        __builtin_amdgcn_s_barrier();
        const u16* Asr = As[cur];
        const u16* Bsr = Bs[cur];
        bf16x8 fa[4], fb[4];
        #pragma unroll
        for (int mi = 0; mi < 4; ++mi) {
            int row = wm + mi * 16 + l16;
            fa[mi] = *(const bf16x8*)(Asr + row * 32 + ((q ^ (row & 3)) * 8));
            int col = wn + mi * 16 + l16;
            fb[mi] = *(const bf16x8*)(Bsr + col * 32 + ((q ^ (col & 3)) * 8));
        }
        #pragma unroll
        for (int mi = 0; mi < 4; ++mi)
            #pragma unroll
            for (int ni = 0; ni < 4; ++ni)
                acc[mi][ni] = __builtin_amdgcn_mfma_f32_16x16x32_bf16(fa[mi], fb[ni], acc[mi][ni], 0, 0, 0);
        __builtin_amdgcn_s_barrier();
        cur += 1; if (cur >= 3) cur -= 3;
    }
#undef STAGE_T
    // ---- fused mf epilogue ----
    int base = 2 * np1;
    #pragma unroll
    for (int mi = 0; mi < 4; ++mi) {
        #pragma unroll
        for (int r = 0; r < 4; ++r) {
            int row = bm + wm + mi * 16 + q * 4 + r;
            bool okrow = (row < M);
            float pe[8] = {0.f,0.f,0.f,0.f,0.f,0.f,0.f,0.f};
            float pd[8] = {0.f,0.f,0.f,0.f,0.f,0.f,0.f,0.f};
            #pragma unroll
            for (int ni = 0; ni < 4; ++ni) {
                int cf = bn + wn + ni * 16 + l16;
                float v = selu_f(acc[mi][ni][r] * 0.125f + bias[cf]);
                if (okrow && afbN)
                    afbN[(size_t)row * Kp1 + base + cf] = f2bf(v);
                const float* fr = fs1 + (size_t)(base + cf) * 8;
                const float* dr = fd1 + (size_t)(base + cf) * 8;
                float4 fra = *(const float4*)(fr);
                float4 frb = *(const float4*)(fr + 4);
                float4 dra = *(const float4*)(dr);
                float4 drb = *(const float4*)(dr + 4);
                pe[0] += v * fra.x; pe[1] += v * fra.y; pe[2] += v * fra.z; pe[3] += v * fra.w;
                pe[4] += v * frb.x; pe[5] += v * frb.y; pe[6] += v * frb.z; pe[7] += v * frb.w;
                pd[0] += v * dra.x; pd[1] += v * dra.y; pd[2] += v * dra.z; pd[3] += v * dra.w;
                pd[4] += v * drb.x; pd[5] += v * drb.y; pd[6] += v * drb.z; pd[7] += v * drb.w;
            }
            #pragma unroll
            for (int off = 1; off <= 8; off <<= 1) {
                #pragma unroll
                for (int h = 0; h < 8; ++h) {
                    pe[h] += __shfl_xor(pe[h], off);
                    pd[h] += __shfl_xor(pd[h], off);
                }
            }
            if (okrow && l16 == 0) {
                #pragma unroll
                for (int h = 0; h < 8; ++h) {
                    atomicAdd(&esN[row * 8 + h], pe[h]);
                    atomicAdd(&edN[row * 8 + h], pd[h]);
                }
            }
        }
    }
}

// ---------------- layer 4: fused softmax + coords -> output (wave per node) ----------------
__global__ void k_final(const float* __restrict__ es, const float* __restrict__ ed,
                        const int* __restrict__ cnt, const int* __restrict__ ssrcb,
                        const float* __restrict__ cprev, float* __restrict__ outp) {
    int wid = (blockIdx.x * blockDim.x + threadIdx.x) >> 6;
    int lane = threadIdx.x & 63;
    if (wid >= N_NODES) return;
    int n = wid;
    int deg = cnt[n];
    if (deg > MAXDEG) deg = MAXDEG;
    const int* row = ssrcb + (size_t)n * MAXDEG;
    int h = lane & 7, ei = lane >> 3;
    float edh = ed[n * 8 + h];
    float m = -1e30f;
    for (int b = 0; b < deg; b += 8) {
        int e = b + ei;
        if (e < deg) {
            int src = row[e];
            float x = es[src * 8 + h] + edh;
            x = x > 0.f ? x : 0.2f * x;
            m = fmaxf(m, x);
        }
    }
    m = fmaxf(m, __shfl_xor(m, 8));
    m = fmaxf(m, __shfl_xor(m, 16));
    m = fmaxf(m, __shfl_xor(m, 32));
    float ssum = 0.f;
    for (int b = 0; b < deg; b += 8) {
        int e = b + ei;
        if (e < deg) {
            int src = row[e];
            float x = es[src * 8 + h] + edh;
            x = x > 0.f ? x : 0.2f * x;
            ssum += __expf(x - m);
        }
    }
    ssum += __shfl_xor(ssum, 8);
    ssum += __shfl_xor(ssum, 16);
    ssum += __shfl_xor(ssum, 32);
    float inv = 1.f / ssum;
    float oc0 = 0.f, oc1 = 0.f;
    for (int b = 0; b < deg; b += 8) {
        int e = b + ei;
        if (e < deg) {
            int src = row[e];
            float x = es[src * 8 + h] + edh;
            x = x > 0.f ? x : 0.2f * x;
            float w = __expf(x - m) * inv;
            w += __shfl_xor(w, 1);
            w += __shfl_xor(w, 2);
            w += __shfl_xor(w, 4);
            if (h == 0) {
                oc0 += w * cprev[src * 2];
                oc1 += w * cprev[src * 2 + 1];
            }
        }
    }
    oc0 += __shfl_xor(oc0, 8);  oc1 += __shfl_xor(oc1, 8);
    oc0 += __shfl_xor(oc0, 16); oc1 += __shfl_xor(oc1, 16);
    oc0 += __shfl_xor(oc0, 32); oc1 += __shfl_xor(oc1, 32);
    if (lane == 0) {
        oc0 *= 0.025f; oc1 *= 0.025f;
        float a0 = cprev[n * 2], a1 = cprev[n * 2 + 1];
        outp[n * 2]     = (a0 == 0.f) ? 0.f : ((a0 == 1.f) ? 1.f : oc0);
        outp[n * 2 + 1] = (a1 == 1.f) ? 1.f : ((a1 == 0.f) ? 0.f : oc1);
    }
}

extern "C" void kernel_launch(void* const* d_in, const int* in_sizes, int n_in,
                              void* d_out, int out_size, void* d_ws, size_t ws_size,
                              hipStream_t stream) {
    const float* data = (const float*)d_in[0];
    const int* ei = (const int*)d_in[1];
    const float* W0 = (const float*)d_in[2];
    const float* b0 = (const float*)d_in[3];
    int E = in_sizes[1] / 2;
    int Esz = E + N_NODES;
    int gE = (Esz + 255) / 256;

    char* wp = (char*)d_ws;
    size_t off = 0;
    auto alloc = [&](size_t bytes) {
        void* p = wp + off;
        off += (bytes + 1023) & ~(size_t)1023;
        return p;
    };
    u16*   g     = (u16*)alloc((size_t)N_NODES * 8 * 576 * 2);
    u16*   T1    = (u16*)alloc((size_t)512 * 8 * 288 * 2);
    u16*   T2    = (u16*)alloc((size_t)256 * 8 * 544 * 2);
    u16*   T3    = (u16*)alloc((size_t)128 * 8 * 288 * 2);
    u16*   afbA  = (u16*)alloc((size_t)N_NODES * 576 * 2);   // parity 0
    u16*   afbB  = (u16*)alloc((size_t)N_NODES * 576 * 2);   // parity 1
    float* esA   = (float*)alloc((size_t)N_NODES * 8 * 4);
    float* esB   = (float*)alloc((size_t)N_NODES * 8 * 4);
    float* edA   = (float*)alloc((size_t)N_NODES * 8 * 4);
    float* edB   = (float*)alloc((size_t)N_NODES * 8 * 4);
    float* fsAll = (float*)alloc((size_t)4 * 516 * 8 * 4);
    float* fdAll = (float*)alloc((size_t)4 * 516 * 8 * 4);
    float* c0    = (float*)alloc(N_NODES * 2 * 4);
    float* c1    = (float*)alloc(N_NODES * 2 * 4);
    float* c2    = (float*)alloc(N_NODES * 2 * 4);
    float* c3    = (float*)alloc(N_NODES * 2 * 4);
    int* cnt   = (int*)alloc(N_NODES * 4);
    int* ssrcb = (int*)alloc((size_t)N_NODES * MAXDEG * 4);

    struct LP { const float *W, *as, *ad, *bs; int K, C; };
    LP L[4] = {
        {(const float*)d_in[4],  (const float*)d_in[5],  (const float*)d_in[6],  (const float*)d_in[7],  258, 512},
        {(const float*)d_in[8],  (const float*)d_in[9],  (const float*)d_in[10], (const float*)d_in[11], 516, 256},
        {(const float*)d_in[12], (const float*)d_in[13], (const float*)d_in[14], (const float*)d_in[15], 262, 128},
        {(const float*)d_in[16], (const float*)d_in[17], (const float*)d_in[18], (const float*)d_in[19], 136, 20},
    };

    u16*   afb2[2] = {afbA, afbB};
    float* esb[2]  = {esA, esB};
    float* edb[2]  = {edA, edB};
    float* cbuf[4] = {c0, c1, c2, c3};
    u16* Tb[3] = {T1, T2, T3};
    const int KpL[4] = {288, 544, 288, 160};   // Kp of layer l (1-based l = idx+1)

    // 1) prep (fold + fat vectorized wtr + zero cnt)
    k_prep<<<516 + 632 + 1, 256, 0, stream>>>(
        L[0].W, L[1].W, L[2].W, L[3].W,
        L[0].as, L[1].as, L[2].as, L[3].as,
        L[0].ad, L[1].ad, L[2].ad, L[3].ad,
        fsAll, fdAll, T1, T2, T3, cnt);

    // 2) bucket fill + mf layer-1 (layer 1 -> parity 1 buffers)
    k_fmf1b<<<gE + N_NODES, 256, 0, stream>>>(
        ei, cnt, ssrcb, E, Esz, gE,
        data, W0, b0,
        fsAll + 0, fdAll + 0, afb2[1], esb[1], edb[1], c0);

    // 3) per-layer: gag (softmax+gather+coords + next-layer init) -> gemm (+fused mf)
    for (int li = 0; li < 3; ++li) {
        int l = li + 1;                 // current layer (1-based)
        int cu = l & 1, nx = (l + 1) & 1;
        int KpC = KpL[li];              // current layer Kp: 288 / 544 / 288
        int KK = 8 * KpC;
        int np1 = li + 2;
        int K1  = (li < 2) ? L[li + 1].K : 0;
        int Kp1 = (li < 2) ? KpL[li + 1] : 0;
        const float* fs1 = fsAll + (size_t)(li + 1) * 516 * 8;
        const float* fd1 = fdAll + (size_t)(li + 1) * 516 * 8;
        u16* afbN = (li < 2) ? afb2[nx] : (u16*)nullptr;
        const float* p2 = (np1 >= 3) ? cbuf[li - 1] : nullptr;
        const float* p3 = (np1 >= 4) ? cbuf[li - 2] : nullptr;

        int gG = (N_NODES + 3) / 4;
        if (KpC == 544)
            k_gag3<5><<<gG, 256, 0, stream>>>(esb[cu], edb[cu], cnt, ssrcb,
                                              cbuf[li], afb2[cu], g, cbuf[li + 1], KpC,
                                              np1, K1, Kp1, fs1, fd1,
                                              esb[nx], edb[nx], afbN, p2, p3);
        else
            k_gag3<3><<<gG, 256, 0, stream>>>(esb[cu], edb[cu], cnt, ssrcb,
                                              cbuf[li], afb2[cu], g, cbuf[li + 1], KpC,
                                              np1, K1, Kp1, fs1, fd1,
                                              esb[nx], edb[nx], afbN, p2, p3);

        int NC = L[li].C;
        int nbx = NC / 128;
        int nby = (N_NODES + 127) / 128;
        int ntile = nbx * nby;          // 160 / 80 / 40 — all % 8 == 0
        k_gemm_f<<<ntile, 256, 0, stream>>>(
            g, Tb[li], N_NODES, KK, NC, nbx,
            L[li].bs, np1, Kp1, fs1, fd1,
            esb[nx], edb[nx], afbN);
    }

    // 4) layer 4: final softmax + coords -> output (reads parity-0 es/ed)
    k_final<<<(N_NODES + 3) / 4, 256, 0, stream>>>(esb[0], edb[0], cnt, ssrcb, cbuf[3],
                                                   (float*)d_out);
}

// Round 13
// 324.801 us; speedup vs baseline: 1.6268x; 1.6268x over previous
//
#include <hip/hip_runtime.h>

#define N_NODES 5000
#define NH 8
#define MAXDEG 128

typedef unsigned short u16;
typedef short bf16x8 __attribute__((ext_vector_type(8)));
typedef float f32x4 __attribute__((ext_vector_type(4)));

static __device__ __forceinline__ float selu_f(float x) {
    const float sc = 1.0507009873554805f;
    const float al = 1.6732632423543772f;
    return x > 0.f ? sc * x : sc * al * (__expf(x) - 1.f);
}

static __device__ __forceinline__ u16 f2bf(float x) {
    union { float f; unsigned u; } v; v.f = x;
    unsigned r = v.u + 0x7fff + ((v.u >> 16) & 1);
    return (u16)(r >> 16);
}

static __device__ __forceinline__ float bf2f(unsigned hi16) {
    union { unsigned u; float f; } v; v.u = hi16 << 16;
    return v.f;
}

// async global->LDS, 16B per lane; LDS dest is wave-uniform base + lane*16
#define GL2LDS16(gp, lp)                                                        \
    __builtin_amdgcn_global_load_lds(                                           \
        (const __attribute__((address_space(1))) void*)(gp),                    \
        (__attribute__((address_space(3))) void*)(lp), 16, 0, 0)

// intra-wave LDS fence (lockstep wave64 handoff, no s_barrier needed)
#define WAVE_LDS_FENCE() asm volatile("s_waitcnt lgkmcnt(0)" ::: "memory")

// ---------------- k_prep v2: vectorized fold + fat wtr + (tail) zero counters ----
__global__ __launch_bounds__(256) void k_prep(
        const float* W1, const float* W2, const float* W3, const float* W4,
        const float* s1, const float* s2, const float* s3, const float* s4,
        const float* d1, const float* d2, const float* d3, const float* d4,
        float* __restrict__ fsAll, float* __restrict__ fdAll,
        u16* T1, u16* T2, u16* T3, int* __restrict__ cnt) {
    const int Ks[4] = {258, 516, 262, 136};
    const int Cs[4] = {512, 256, 128, 20};
    const int NB0 = 16 * 18;   // li0: C=512, KK=2304
    const int NB1 = 8  * 34;   // li1: C=256, KK=4352
    const int NB2 = 4  * 18;   // li2: C=128, KK=2304
    const int NWTR = NB0 + NB1 + NB2;   // 632
    int bid = blockIdx.x;
    if (bid < 516) {
        int li = bid / 129;
        int k = (bid % 129) * 4 + (threadIdx.x >> 6);
        int lane = threadIdx.x & 63;
        if (k >= Ks[li]) return;
        const float* W  = (li == 0) ? W1 : (li == 1) ? W2 : (li == 2) ? W3 : W4;
        const float* as = (li == 0) ? s1 : (li == 1) ? s2 : (li == 2) ? s3 : s4;
        const float* ad = (li == 0) ? d1 : (li == 1) ? d2 : (li == 2) ? d3 : d4;
        int C = Cs[li];
        float s[8] = {0.f,0.f,0.f,0.f,0.f,0.f,0.f,0.f};
        float d[8] = {0.f,0.f,0.f,0.f,0.f,0.f,0.f,0.f};
        const float* wr = W + (size_t)k * 8 * C;
        for (int c = lane * 4; c < C; c += 256) {
            #pragma unroll
            for (int h = 0; h < 8; ++h) {
                float4 wv = *(const float4*)(wr + h * C + c);
                float4 sv = *(const float4*)(as + h * C + c);
                float4 dv = *(const float4*)(ad + h * C + c);
                s[h] += wv.x * sv.x + wv.y * sv.y + wv.z * sv.z + wv.w * sv.w;
                d[h] += wv.x * dv.x + wv.y * dv.y + wv.z * dv.z + wv.w * dv.w;
            }
        }
        #pragma unroll
        for (int off = 32; off >= 1; off >>= 1) {
            #pragma unroll
            for (int h = 0; h < 8; ++h) {
                s[h] += __shfl_xor(s[h], off);
                d[h] += __shfl_xor(d[h], off);
            }
        }
        if (lane == 0) {
            float* fo = fsAll + (size_t)li * 516 * 8 + k * 8;
            float* go = fdAll + (size_t)li * 516 * 8 + k * 8;
            #pragma unroll
            for (int h = 0; h < 8; ++h) { fo[h] = s[h]; go[h] = d[h]; }
        }
    } else if (bid < 516 + NWTR) {
        int w = bid - 516;
        int li, rem, nc;
        if (w < NB0)            { li = 0; rem = w;             nc = 16; }
        else if (w < NB0 + NB1) { li = 1; rem = w - NB0;       nc = 8;  }
        else                    { li = 2; rem = w - NB0 - NB1; nc = 4;  }
        const int Kps[3] = {288, 544, 288};
        int C = Cs[li], K = Ks[li], Kp = Kps[li], KK = 8 * Kp;
        int c0 = (rem % nc) * 32;
        int jb = (rem / nc) * 128;
        const float* W = (li == 0) ? W1 : (li == 1) ? W2 : W3;
        u16* Wt2 = (li == 0) ? T1 : (li == 1) ? T2 : T3;
        __shared__ float tile[32][33];
        int t = threadIdx.x;
        int kr = t >> 3, f = t & 7;
        #pragma unroll
        for (int jt = 0; jt < 4; ++jt) {
            int j0 = jb + jt * 32;
            int h = j0 / Kp, k0 = j0 % Kp;
            int gk = k0 + kr;
            float4 v = {0.f, 0.f, 0.f, 0.f};
            if (gk < K) v = *(const float4*)(W + (size_t)gk * (8 * C) + h * C + c0 + f * 4);
            tile[kr][f * 4 + 0] = v.x;
            tile[kr][f * 4 + 1] = v.y;
            tile[kr][f * 4 + 2] = v.z;
            tile[kr][f * 4 + 3] = v.w;
            __syncthreads();
            int cr = kr, kc0 = f * 4;
            ushort4 o;
            o.x = f2bf(tile[kc0 + 0][cr]);
            o.y = f2bf(tile[kc0 + 1][cr]);
            o.z = f2bf(tile[kc0 + 2][cr]);
            o.w = f2bf(tile[kc0 + 3][cr]);
            *(ushort4*)(Wt2 + (size_t)(c0 + cr) * KK + j0 + kc0) = o;
            __syncthreads();
        }
    } else {
        for (int i = threadIdx.x; i < N_NODES; i += 256) cnt[i] = 0;
    }
}

// ---------------- k_fmf1b: bucketed fill + layer-1 mf in one dispatch ----------------
__global__ __launch_bounds__(256) void k_fmf1b(
        const int* __restrict__ ei, int* __restrict__ cnt,
        int* __restrict__ ssrcb, int E, int Esz, int gE,
        const float* __restrict__ data, const float* __restrict__ W0,
        const float* __restrict__ b0,
        const float* __restrict__ fs, const float* __restrict__ fd,
        u16* __restrict__ afb, float* __restrict__ es, float* __restrict__ ed,
        float* __restrict__ c0out) {
    int bid = blockIdx.x, t = threadIdx.x;
    if (bid < gE) {
        int e = bid * 256 + t;
        if (e >= Esz) return;
        int src, dst;
        if (e < E) { src = ei[e]; dst = ei[E + e]; }
        else       { src = e - E; dst = src; }
        int pos = atomicAdd(&cnt[dst], 1);
        if (pos < MAXDEG) ssrcb[dst * MAXDEG + pos] = src;
        return;
    }
    const int FC = 256, K = 258, Kp = 288;
    int n = bid - gE;
    __shared__ float drow[10];
    if (t < 10) drow[t] = data[n * 10 + t];
    __syncthreads();
    float pes[8] = {0.f,0.f,0.f,0.f,0.f,0.f,0.f,0.f};
    float ped[8] = {0.f,0.f,0.f,0.f,0.f,0.f,0.f,0.f};
    u16* rowb = afb + (size_t)n * Kp;
    for (int cf2 = t; 2 * cf2 < FC; cf2 += 256) {
        int cf = 2 * cf2;
        float2 bb = *(const float2*)(b0 + cf);
        float v0 = bb.x, v1 = bb.y;
        #pragma unroll
        for (int k = 0; k < 10; ++k) {
            float2 ww = *(const float2*)(W0 + k * 256 + cf);
            v0 += drow[k] * ww.x;
            v1 += drow[k] * ww.y;
        }
        v0 = selu_f(v0); v1 = selu_f(v1);
        int c = 2 + cf;
        *(unsigned*)(rowb + c) = (unsigned)f2bf(v0) | ((unsigned)f2bf(v1) << 16);
        const float* fsr = fs + c * 8;
        const float* fdr = fd + c * 8;
        #pragma unroll
        for (int h = 0; h < 8; ++h) {
            pes[h] += v0 * fsr[h] + v1 * fsr[8 + h];
            ped[h] += v0 * fdr[h] + v1 * fdr[8 + h];
        }
    }
    if (t < 2) {
        float v = drow[t];
        c0out[n * 2 + t] = v;
        rowb[t] = f2bf(v);
        #pragma unroll
        for (int h = 0; h < 8; ++h) { pes[h] += v * fs[t * 8 + h]; ped[h] += v * fd[t * 8 + h]; }
    }
    for (int c = K + t; c < Kp; c += 256) rowb[c] = 0;
    #pragma unroll
    for (int off = 32; off >= 1; off >>= 1) {
        #pragma unroll
        for (int h = 0; h < 8; ++h) {
            pes[h] += __shfl_xor(pes[h], off);
            ped[h] += __shfl_xor(ped[h], off);
        }
    }
    __shared__ float red[4][16];
    int wv = t >> 6, ln = t & 63;
    if (ln == 0) {
        #pragma unroll
        for (int h = 0; h < 8; ++h) { red[wv][h] = pes[h]; red[wv][8 + h] = ped[h]; }
    }
    __syncthreads();
    if (t < 16) {
        float s = red[0][t] + red[1][t] + red[2][t] + red[3][t];
        if (t < 8) es[n * 8 + t] = s;
        else       ed[n * 8 + (t - 8)] = s;
    }
}

// ---------------- k_mf: block per node, layers 2..4 (paired-cf) ----------------
// np==4 (layer 4): afb is dead downstream (k_final gathers coords only) -> skip
// rowb stores + zero-pad; es/ed math unchanged.
__global__ __launch_bounds__(256) void k_mf(const float* p0, const float* p1,
                                            const float* p2, const float* p3, int np,
                                            const u16* __restrict__ facc,
                                            const float* __restrict__ biasp,
                                            int split, int MN, int FC, int K, int Kp,
                                            const float* __restrict__ fs,
                                            const float* __restrict__ fd,
                                            u16* __restrict__ afb,
                                            float* __restrict__ es, float* __restrict__ ed) {
    int n = blockIdx.x, t = threadIdx.x;
    bool wr = (np < 4);
    float pes[8] = {0.f,0.f,0.f,0.f,0.f,0.f,0.f,0.f};
    float ped[8] = {0.f,0.f,0.f,0.f,0.f,0.f,0.f,0.f};
    u16* rowb = afb + (size_t)n * Kp;
    for (int cf2 = t; 2 * cf2 < FC; cf2 += 256) {
        int cf = 2 * cf2;
        float s0 = 0.f, s1 = 0.f;
        for (int z = 0; z < split; ++z) {
            unsigned pr = *(const unsigned*)(facc + (size_t)z * MN + (size_t)n * FC + cf);
            s0 += bf2f(pr & 0xffff);
            s1 += bf2f(pr >> 16);
        }
        float2 bb = *(const float2*)(biasp + cf);
        float v0 = selu_f(s0 * 0.125f + bb.x);
        float v1 = selu_f(s1 * 0.125f + bb.y);
        int c = 2 * np + cf;
        if (wr)
            *(unsigned*)(rowb + c) = (unsigned)f2bf(v0) | ((unsigned)f2bf(v1) << 16);
        const float* fsr = fs + c * 8;
        const float* fdr = fd + c * 8;
        #pragma unroll
        for (int h = 0; h < 8; ++h) {
            pes[h] += v0 * fsr[h] + v1 * fsr[8 + h];
            ped[h] += v0 * fdr[h] + v1 * fdr[8 + h];
        }
    }
    if (t < 2 * np) {
        const float* p = (t < 2) ? p0 : (t < 4) ? p1 : (t < 6) ? p2 : p3;
        float v = p[n * 2 + (t & 1)];
        if (wr) rowb[t] = f2bf(v);
        #pragma unroll
        for (int h = 0; h < 8; ++h) { pes[h] += v * fs[t * 8 + h]; ped[h] += v * fd[t * 8 + h]; }
    }
    if (wr)
        for (int c = K + t; c < Kp; c += 256) rowb[c] = 0;
    #pragma unroll
    for (int off = 32; off >= 1; off >>= 1) {
        #pragma unroll
        for (int h = 0; h < 8; ++h) {
            pes[h] += __shfl_xor(pes[h], off);
            ped[h] += __shfl_xor(ped[h], off);
        }
    }
    __shared__ float red[4][16];
    int wv = t >> 6, ln = t & 63;
    if (ln == 0) {
        #pragma unroll
        for (int h = 0; h < 8; ++h) { red[wv][h] = pes[h]; red[wv][8 + h] = ped[h]; }
    }
    __syncthreads();
    if (t < 16) {
        float s = red[0][t] + red[1][t] + red[2][t] + red[3][t];
        if (t < 8) es[n * 8 + t] = s;
        else       ed[n * 8 + (t - 8)] = s;
    }
}

// ---------------- gag: WAVE per node (4 nodes / 256-block); bucketed adjacency ----
template <int S>
__global__ __launch_bounds__(256) void k_gag2(const float* __restrict__ es,
                            const float* __restrict__ ed,
                            const int* __restrict__ cnt, const int* __restrict__ ssrcb,
                            const float* __restrict__ cprev, const u16* __restrict__ afb,
                            u16* __restrict__ g, float* __restrict__ cnext, int Kp) {
    __shared__ float la_s[4][128 * 8];
    __shared__ int   ls_s[4][128];
    __shared__ float linv_s[4][8];
    int w4 = threadIdx.x >> 6, lane = threadIdx.x & 63;
    int n = blockIdx.x * 4 + w4;
    if (n >= N_NODES) return;
    float* la = la_s[w4];
    int*   ls = ls_s[w4];
    float* linv = linv_s[w4];

    int deg = cnt[n];
    if (deg > MAXDEG) deg = MAXDEG;
    const int* row = ssrcb + (size_t)n * MAXDEG;
    for (int i = lane; i < deg; i += 64) ls[i] = row[i];
    WAVE_LDS_FENCE();

    int h = lane & 7, ei = lane >> 3;
    float edh = ed[n * 8 + h];
    float m = -1e30f;
    for (int b = 0; b < deg; b += 8) {
        int e = b + ei;
        if (e < deg) {
            float x = es[ls[e] * 8 + h] + edh;
            x = x > 0.f ? x : 0.2f * x;
            la[e * 8 + h] = x;
            m = fmaxf(m, x);
        }
    }
    m = fmaxf(m, __shfl_xor(m, 8));
    m = fmaxf(m, __shfl_xor(m, 16));
    m = fmaxf(m, __shfl_xor(m, 32));
    WAVE_LDS_FENCE();
    float ssum = 0.f;
    for (int b = 0; b < deg; b += 8) {
        int e = b + ei;
        if (e < deg) {
            float v = __expf(la[e * 8 + h] - m);
            la[e * 8 + h] = v;
            ssum += v;
        }
    }
    ssum += __shfl_xor(ssum, 8);
    ssum += __shfl_xor(ssum, 16);
    ssum += __shfl_xor(ssum, 32);
    if (lane < 8) linv[lane] = 1.f / ssum;
    WAVE_LDS_FENCE();

    int nW = Kp >> 1;
    float linv8[8];
    #pragma unroll
    for (int h2 = 0; h2 < 8; ++h2) linv8[h2] = linv[h2];

    float acc[8][2 * S];
    #pragma unroll
    for (int h2 = 0; h2 < 8; ++h2)
        #pragma unroll
        for (int s = 0; s < 2 * S; ++s) acc[h2][s] = 0.f;
    int e = 0;
    for (; e + 3 < deg; e += 4) {
        const unsigned* r0 = (const unsigned*)(afb + (size_t)ls[e] * Kp);
        const unsigned* r1 = (const unsigned*)(afb + (size_t)ls[e + 1] * Kp);
        const unsigned* r2 = (const unsigned*)(afb + (size_t)ls[e + 2] * Kp);
        const unsigned* r3 = (const unsigned*)(afb + (size_t)ls[e + 3] * Kp);
        unsigned v0[S], v1[S], v2[S], v3[S];
        #pragma unroll
        for (int s = 0; s < S; ++s) {
            int w = lane + 64 * s;
            bool ok = (w < nW);
            v0[s] = ok ? r0[w] : 0u;
            v1[s] = ok ? r1[w] : 0u;
            v2[s] = ok ? r2[w] : 0u;
            v3[s] = ok ? r3[w] : 0u;
        }
        float a0[8], a1[8], a2[8], a3[8];
        #pragma unroll
        for (int h2 = 0; h2 < 8; ++h2) {
            a0[h2] = la[(e + 0) * 8 + h2];
            a1[h2] = la[(e + 1) * 8 + h2];
            a2[h2] = la[(e + 2) * 8 + h2];
            a3[h2] = la[(e + 3) * 8 + h2];
        }
        #pragma unroll
        for (int s = 0; s < S; ++s) {
            float x0 = bf2f(v0[s] & 0xffff), y0 = bf2f(v0[s] >> 16);
            float x1 = bf2f(v1[s] & 0xffff), y1 = bf2f(v1[s] >> 16);
            float x2 = bf2f(v2[s] & 0xffff), y2 = bf2f(v2[s] >> 16);
            float x3 = bf2f(v3[s] & 0xffff), y3 = bf2f(v3[s] >> 16);
            #pragma unroll
            for (int h2 = 0; h2 < 8; ++h2) {
                acc[h2][2 * s]     += a0[h2] * x0 + a1[h2] * x1 + a2[h2] * x2 + a3[h2] * x3;
                acc[h2][2 * s + 1] += a0[h2] * y0 + a1[h2] * y1 + a2[h2] * y2 + a3[h2] * y3;
            }
        }
    }
    for (; e < deg; ++e) {
        const unsigned* r0 = (const unsigned*)(afb + (size_t)ls[e] * Kp);
        unsigned v0[S];
        #pragma unroll
        for (int s = 0; s < S; ++s) {
            int w = lane + 64 * s;
            v0[s] = (w < nW) ? r0[w] : 0u;
        }
        float a0[8];
        #pragma unroll
        for (int h2 = 0; h2 < 8; ++h2) a0[h2] = la[e * 8 + h2];
        #pragma unroll
        for (int s = 0; s < S; ++s) {
            float x0 = bf2f(v0[s] & 0xffff), y0 = bf2f(v0[s] >> 16);
            #pragma unroll
            for (int h2 = 0; h2 < 8; ++h2) {
                acc[h2][2 * s]     += a0[h2] * x0;
                acc[h2][2 * s + 1] += a0[h2] * y0;
            }
        }
    }
    unsigned* grw = (unsigned*)(g + (size_t)n * 8 * Kp);
    #pragma unroll
    for (int s = 0; s < S; ++s) {
        int w = lane + 64 * s;
        if (w < nW) {
            #pragma unroll
            for (int h2 = 0; h2 < 8; ++h2) {
                float iv = linv8[h2];
                unsigned lo = f2bf(acc[h2][2 * s] * iv);
                unsigned hi = f2bf(acc[h2][2 * s + 1] * iv);
                grw[h2 * nW + w] = lo | (hi << 16);
            }
        }
    }
    float oc0 = 0.f, oc1 = 0.f;
    for (int i = lane; i < deg; i += 64) {
        float wsum = 0.f;
        #pragma unroll
        for (int h2 = 0; h2 < 8; ++h2) wsum += la[i * 8 + h2] * linv8[h2];
        int src = ls[i];
        oc0 += wsum * cprev[src * 2];
        oc1 += wsum * cprev[src * 2 + 1];
    }
    #pragma unroll
    for (int off = 1; off <= 32; off <<= 1) {
        oc0 += __shfl_xor(oc0, off);
        oc1 += __shfl_xor(oc1, off);
    }
    if (lane == 0) {
        oc0 *= 0.025f; oc1 *= 0.025f;
        float a0 = cprev[n * 2], a1 = cprev[n * 2 + 1];
        cnext[n * 2]     = (a0 == 0.f) ? 0.f : ((a0 == 1.f) ? 1.f : oc0);
        cnext[n * 2 + 1] = (a1 == 1.f) ? 1.f : ((a1 == 0.f) ? 0.f : oc1);
    }
}

// ---------------- split-K MFMA GEMM, 128x128 tile, 3-deep pipelined gl2lds ----------------
// 1D grid with bijective XCD-chunked remap (T1): oo = (o&7)*(T/8) + (o>>3)
// (valid: all ntile % 8 == 0). Decode bx-fastest, z-next, by-outer.
__global__ __launch_bounds__(256) void k_gemm_s(const u16* __restrict__ A,
                                                const u16* __restrict__ Bt,
                                                u16* __restrict__ facc16,
                                                int M, int KK, int NC, int kchunk, int MN,
                                                int nbx, int split) {
    __shared__ u16 As[3][128 * 32];
    __shared__ u16 Bs[3][128 * 32];
    int tid = threadIdx.x;
    int wave = tid >> 6, lane = tid & 63;

    int T = gridDim.x;
    int per8 = T >> 3;
    int o = blockIdx.x;
    int oo = (o & 7) * per8 + (o >> 3);
    int grp = split * nbx;
    int by = oo / grp;
    int rem = oo - by * grp;
    int z = rem / nbx;
    int bx = rem - z * nbx;

    int bm = by * 128, bn = bx * 128;
    int kbeg = z * kchunk, kend = min(KK, kbeg + kchunk);
    int wm = (wave >> 1) * 64, wn = (wave & 1) * 64;
    int l16 = lane & 15, q = lane >> 4;
    f32x4 acc[4][4] = {};

    int seg0 = wave * 128 + lane;
    int seg1 = seg0 + 64;
    int row0 = seg0 >> 2, sq0 = (seg0 & 3) ^ (row0 & 3);
    int row1 = seg1 >> 2, sq1 = (seg1 & 3) ^ (row1 & 3);
    const u16* ga0 = A  + (size_t)(bm + row0) * KK + sq0 * 8;
    const u16* ga1 = A  + (size_t)(bm + row1) * KK + sq1 * 8;
    const u16* gb0 = Bt + (size_t)(bn + row0) * KK + sq0 * 8;
    const u16* gb1 = Bt + (size_t)(bn + row1) * KK + sq1 * 8;
    int lo0 = (wave * 2 + 0) * 512;
    int lo1 = (wave * 2 + 1) * 512;

#define STAGE_T(buf, kk)                          \
    do {                                          \
        GL2LDS16(ga0 + (kk), &As[buf][lo0]);      \
        GL2LDS16(ga1 + (kk), &As[buf][lo1]);      \
        GL2LDS16(gb0 + (kk), &Bs[buf][lo0]);      \
        GL2LDS16(gb1 + (kk), &Bs[buf][lo1]);      \
    } while (0)

    STAGE_T(0, kbeg);
    if (kbeg + 32 < kend) STAGE_T(1, kbeg + 32);
    int cur = 0;
    for (int k0 = kbeg; k0 < kend; k0 += 32) {
        if (k0 + 64 < kend) {
            int nb = cur + 2; if (nb >= 3) nb -= 3;
            STAGE_T(nb, k0 + 64);
            asm volatile("s_waitcnt vmcnt(8)" ::: "memory");
        } else if (k0 + 32 < kend) {
            asm volatile("s_waitcnt vmcnt(4)" ::: "memory");
        } else {
            asm volatile("s_waitcnt vmcnt(0)" ::: "memory");
        }
        __builtin_amdgcn_s_barrier();
        const u16* Asr = As[cur];
        const u16* Bsr = Bs[cur];
        bf16x8 fa[4], fb[4];
        #pragma unroll
        for (int mi = 0; mi < 4; ++mi) {
            int row = wm + mi * 16 + l16;
            fa[mi] = *(const bf16x8*)(Asr + row * 32 + ((q ^ (row & 3)) * 8));
            int col = wn + mi * 16 + l16;
            fb[mi] = *(const bf16x8*)(Bsr + col * 32 + ((q ^ (col & 3)) * 8));
        }
        #pragma unroll
        for (int mi = 0; mi < 4; ++mi)
            #pragma unroll
            for (int ni = 0; ni < 4; ++ni)
                acc[mi][ni] = __builtin_amdgcn_mfma_f32_16x16x32_bf16(fa[mi], fb[ni], acc[mi][ni], 0, 0, 0);
        __builtin_amdgcn_s_barrier();
        cur += 1; if (cur >= 3) cur -= 3;
    }
#undef STAGE_T
    u16* out = facc16 + (size_t)z * MN;
    #pragma unroll
    for (int mi = 0; mi < 4; ++mi) {
        int row0s = bm + wm + mi * 16 + q * 4;
        #pragma unroll
        for (int ni = 0; ni < 4; ++ni) {
            int col = bn + wn + ni * 16 + l16;
            #pragma unroll
            for (int r = 0; r < 4; ++r) {
                int row = row0s + r;
                if (row < M) out[(size_t)row * NC + col] = f2bf(acc[mi][ni][r]);
            }
        }
    }
}

// ---------------- layer 4: fused softmax + coords -> output (wave per node) ----------------
__global__ void k_final(const float* __restrict__ es, const float* __restrict__ ed,
                        const int* __restrict__ cnt, const int* __restrict__ ssrcb,
                        const float* __restrict__ cprev, float* __restrict__ outp) {
    int wid = (blockIdx.x * blockDim.x + threadIdx.x) >> 6;
    int lane = threadIdx.x & 63;
    if (wid >= N_NODES) return;
    int n = wid;
    int deg = cnt[n];
    if (deg > MAXDEG) deg = MAXDEG;
    const int* row = ssrcb + (size_t)n * MAXDEG;
    int h = lane & 7, ei = lane >> 3;
    float edh = ed[n * 8 + h];
    float m = -1e30f;
    for (int b = 0; b < deg; b += 8) {
        int e = b + ei;
        if (e < deg) {
            int src = row[e];
            float x = es[src * 8 + h] + edh;
            x = x > 0.f ? x : 0.2f * x;
            m = fmaxf(m, x);
        }
    }
    m = fmaxf(m, __shfl_xor(m, 8));
    m = fmaxf(m, __shfl_xor(m, 16));
    m = fmaxf(m, __shfl_xor(m, 32));
    float ssum = 0.f;
    for (int b = 0; b < deg; b += 8) {
        int e = b + ei;
        if (e < deg) {
            int src = row[e];
            float x = es[src * 8 + h] + edh;
            x = x > 0.f ? x : 0.2f * x;
            ssum += __expf(x - m);
        }
    }
    ssum += __shfl_xor(ssum, 8);
    ssum += __shfl_xor(ssum, 16);
    ssum += __shfl_xor(ssum, 32);
    float inv = 1.f / ssum;
    float oc0 = 0.f, oc1 = 0.f;
    for (int b = 0; b < deg; b += 8) {
        int e = b + ei;
        if (e < deg) {
            int src = row[e];
            float x = es[src * 8 + h] + edh;
            x = x > 0.f ? x : 0.2f * x;
            float w = __expf(x - m) * inv;
            w += __shfl_xor(w, 1);
            w += __shfl_xor(w, 2);
            w += __shfl_xor(w, 4);
            if (h == 0) {
                oc0 += w * cprev[src * 2];
                oc1 += w * cprev[src * 2 + 1];
            }
        }
    }
    oc0 += __shfl_xor(oc0, 8);  oc1 += __shfl_xor(oc1, 8);
    oc0 += __shfl_xor(oc0, 16); oc1 += __shfl_xor(oc1, 16);
    oc0 += __shfl_xor(oc0, 32); oc1 += __shfl_xor(oc1, 32);
    if (lane == 0) {
        oc0 *= 0.025f; oc1 *= 0.025f;
        float a0 = cprev[n * 2], a1 = cprev[n * 2 + 1];
        outp[n * 2]     = (a0 == 0.f) ? 0.f : ((a0 == 1.f) ? 1.f : oc0);
        outp[n * 2 + 1] = (a1 == 1.f) ? 1.f : ((a1 == 0.f) ? 0.f : oc1);
    }
}

extern "C" void kernel_launch(void* const* d_in, const int* in_sizes, int n_in,
                              void* d_out, int out_size, void* d_ws, size_t ws_size,
                              hipStream_t stream) {
    const float* data = (const float*)d_in[0];
    const int* ei = (const int*)d_in[1];
    const float* W0 = (const float*)d_in[2];
    const float* b0 = (const float*)d_in[3];
    int E = in_sizes[1] / 2;
    int Esz = E + N_NODES;
    int gE = (Esz + 255) / 256;

    char* wp = (char*)d_ws;
    size_t off = 0;
    auto alloc = [&](size_t bytes) {
        void* p = wp + off;
        off += (bytes + 1023) & ~(size_t)1023;
        return p;
    };
    u16*   g     = (u16*)alloc((size_t)N_NODES * 8 * 576 * 2);
    u16*   T1    = (u16*)alloc((size_t)512 * 8 * 288 * 2);
    u16*   T2    = (u16*)alloc((size_t)256 * 8 * 544 * 2);
    u16*   T3    = (u16*)alloc((size_t)128 * 8 * 288 * 2);
    u16*   facc  = (u16*)alloc((size_t)8 * N_NODES * 512 * 2);
    u16*   afb   = (u16*)alloc((size_t)N_NODES * 576 * 2);
    float* es    = (float*)alloc((size_t)N_NODES * 8 * 4);
    float* ebd   = (float*)alloc((size_t)N_NODES * 8 * 4);
    float* fsAll = (float*)alloc((size_t)4 * 516 * 8 * 4);
    float* fdAll = (float*)alloc((size_t)4 * 516 * 8 * 4);
    float* c0    = (float*)alloc(N_NODES * 2 * 4);
    float* c1    = (float*)alloc(N_NODES * 2 * 4);
    float* c2    = (float*)alloc(N_NODES * 2 * 4);
    float* c3    = (float*)alloc(N_NODES * 2 * 4);
    int* cnt   = (int*)alloc(N_NODES * 4);
    int* ssrcb = (int*)alloc((size_t)N_NODES * MAXDEG * 4);

    struct LP { const float *W, *as, *ad, *bs; int K, C, split; };
    LP L[4] = {
        {(const float*)d_in[4],  (const float*)d_in[5],  (const float*)d_in[6],  (const float*)d_in[7],  258, 512, 4},
        {(const float*)d_in[8],  (const float*)d_in[9],  (const float*)d_in[10], (const float*)d_in[11], 516, 256, 8},
        {(const float*)d_in[12], (const float*)d_in[13], (const float*)d_in[14], (const float*)d_in[15], 262, 128, 8},
        {(const float*)d_in[16], (const float*)d_in[17], (const float*)d_in[18], (const float*)d_in[19], 136, 20, 1},
    };

    // 1) prep v2 (fold + fat vectorized wtr + zero cnt): 516 + 632 + 1 blocks
    k_prep<<<516 + 632 + 1, 256, 0, stream>>>(
        L[0].W, L[1].W, L[2].W, L[3].W,
        L[0].as, L[1].as, L[2].as, L[3].as,
        L[0].ad, L[1].ad, L[2].ad, L[3].ad,
        fsAll, fdAll, T1, T2, T3, cnt);

    // 2) bucket fill + mf layer-1 (one dispatch)
    k_fmf1b<<<gE + N_NODES, 256, 0, stream>>>(
        ei, cnt, ssrcb, E, Esz, gE,
        data, W0, b0,
        fsAll + 0, fdAll + 0, afb, es, ebd, c0);

    float* cbuf[4] = {c0, c1, c2, c3};
    u16* Tb[3] = {T1, T2, T3};
    int FC[4] = {256, 512, 256, 128};   // feat width consumed by layer li

    for (int li = 0; li < 4; ++li) {
        LP& lp = L[li];
        int Kp = ((lp.K + 31) / 32) * 32;
        int KK = 8 * Kp;

        if (li >= 1) {
            const float* p[4] = {nullptr, nullptr, nullptr, nullptr};
            for (int j = 0; j <= li; ++j) p[j] = cbuf[li - j];
            const float* biasp = L[li - 1].bs;
            int splitp = L[li - 1].split;
            int MNp = N_NODES * FC[li];
            const float* fs = fsAll + (size_t)li * 516 * 8;
            const float* fd = fdAll + (size_t)li * 516 * 8;
            k_mf<<<N_NODES, 256, 0, stream>>>(p[0], p[1], p[2], p[3], li + 1,
                                              facc, biasp, splitp, MNp, FC[li],
                                              lp.K, Kp, fs, fd, afb, es, ebd);
        }
        if (li < 3) {
            int gG = (N_NODES + 3) / 4;
            if (Kp == 544)
                k_gag2<5><<<gG, 256, 0, stream>>>(es, ebd, cnt, ssrcb, cbuf[li], afb,
                                                  g, cbuf[li + 1], Kp);
            else
                k_gag2<3><<<gG, 256, 0, stream>>>(es, ebd, cnt, ssrcb, cbuf[li], afb,
                                                  g, cbuf[li + 1], Kp);
            int MN = N_NODES * lp.C;
            int nbx = lp.C / 128;
            int nby = (N_NODES + 127) / 128;
            int ntile = nbx * nby * lp.split;   // 640 / 640 / 320 — all % 8 == 0
            k_gemm_s<<<ntile, 256, 0, stream>>>(
                g, Tb[li], facc, N_NODES, KK, lp.C, KK / lp.split, MN,
                nbx, lp.split);
        } else {
            k_final<<<(N_NODES + 3) / 4, 256, 0, stream>>>(es, ebd, cnt, ssrcb, cbuf[3],
                                                           (float*)d_out);
        }
    }
}